// Round 1
// baseline (1209.143 us; speedup 1.0000x reference)
//
#include <hip/hip_runtime.h>
#include <hip/hip_bf16.h>

// Problem constants
#define B_DIM 256
#define C_DIM 4096
#define FIN   160
#define FHID  192
#define EPS   1e-5f

// LDS row strides (bf16 elems): 32 data + 8 pad -> 80B row stride
// -> b128 fragment reads land 2-way bank-aliased (free on gfx950, m136)
#define AST 40
#define BST 40

typedef short  short8  __attribute__((ext_vector_type(8)));
typedef float  floatx4 __attribute__((ext_vector_type(4)));

__device__ __forceinline__ short f2bs(float f) {
  __hip_bfloat16 h = __float2bfloat16(f);   // RNE
  return *reinterpret_cast<short*>(&h);
}

__device__ __forceinline__ void cvt_store8(short* dst, const float4& v0, const float4& v1) {
  short8 s;
  s[0] = f2bs(v0.x); s[1] = f2bs(v0.y); s[2] = f2bs(v0.z); s[3] = f2bs(v0.w);
  s[4] = f2bs(v1.x); s[5] = f2bs(v1.y); s[6] = f2bs(v1.z); s[7] = f2bs(v1.w);
  *reinterpret_cast<short8*>(dst) = s;      // 16B aligned store
}

// One workgroup per cell c. 1024 threads = 16 waves in a 4x4 grid:
//   wave row wr (0..3): batch rows [wr*64, wr*64+64)
//   wave col wc (0..3): hidden cols [wc*48, wc*48+48)  (3 n-tiles of 16)
// GEMM1 via mfma_f32_16x16x32_bf16, K=160 in 5 chunks of 32.
__global__ __launch_bounds__(1024) void mlp_fused_kernel(
    const float* __restrict__ x,     // [B, C, FIN]
    const float* __restrict__ W1,    // [C, FHID, FIN]
    const float* __restrict__ gamma, // [C, FHID]
    const float* __restrict__ beta,  // [C, FHID]
    const float* __restrict__ W2,    // [C, 1, FHID]
    const float* __restrict__ b2,    // [C, 1]
    float* __restrict__ out)         // [B, C, 1]
{
  const int c    = blockIdx.x;
  const int tid  = threadIdx.x;
  const int lane = tid & 63;
  const int wave = tid >> 6;     // 0..15
  const int wr   = wave >> 2;    // 0..3
  const int wc   = wave & 3;     // 0..3
  const int l15  = lane & 15;
  const int lg   = lane >> 4;    // 0..3

  __shared__ __align__(16) short Alds[B_DIM * AST];   // 20480 B
  __shared__ __align__(16) short Blds[FHID * BST];    // 15360 B
  __shared__ float psum[4][FHID];
  __shared__ float psq [4][FHID];
  __shared__ float scaleS[FHID];
  __shared__ float shiftS[FHID];
  __shared__ float w2S[FHID];
  __shared__ float rowp[4][B_DIM];

  const float* xc  = x  + (size_t)c * FIN;
  const float* w1c = W1 + (size_t)c * FHID * FIN;

  // Staging assignment: thread t loads 8 contiguous fp32 (2x float4).
  // A: all 1024 threads -> row = t/4 (0..255), k-offset = (t%4)*8
  // B: threads 0..767  -> row = t/4 (0..191), k-offset = (t%4)*8
  const int  arow = tid >> 2;
  const int  aq   = (tid & 3) * 8;
  const bool bact = tid < 768;

  float4 a0, a1, b0, b1;
  {
    const float* pa = xc + (size_t)arow * (C_DIM * FIN) + aq;
    a0 = *reinterpret_cast<const float4*>(pa);
    a1 = *reinterpret_cast<const float4*>(pa + 4);
    if (bact) {
      const float* pb = w1c + arow * FIN + aq;
      b0 = *reinterpret_cast<const float4*>(pb);
      b1 = *reinterpret_cast<const float4*>(pb + 4);
    }
  }

  floatx4 acc[4][3];
  #pragma unroll
  for (int mt = 0; mt < 4; ++mt)
    #pragma unroll
    for (int nt = 0; nt < 3; ++nt)
      acc[mt][nt] = (floatx4)(0.f);

  for (int kc = 0; kc < 5; ++kc) {
    // stage current chunk (bf16) into LDS
    cvt_store8(&Alds[arow * AST + aq], a0, a1);
    if (bact) cvt_store8(&Blds[arow * BST + aq], b0, b1);
    __syncthreads();

    // register-prefetch next chunk; overlaps the MFMA phase below
    if (kc < 4) {
      const int k0 = (kc + 1) * 32;
      const float* pa = xc + (size_t)arow * (C_DIM * FIN) + k0 + aq;
      a0 = *reinterpret_cast<const float4*>(pa);
      a1 = *reinterpret_cast<const float4*>(pa + 4);
      if (bact) {
        const float* pb = w1c + arow * FIN + k0 + aq;
        b0 = *reinterpret_cast<const float4*>(pb);
        b1 = *reinterpret_cast<const float4*>(pb + 4);
      }
    }

    // fragments: A[m=l15][k=lg*8..+7], B[n=l15][k=lg*8..+7] (B^T layout)
    short8 af[4], bf[3];
    #pragma unroll
    for (int mt = 0; mt < 4; ++mt) {
      const int row = wr * 64 + mt * 16 + l15;
      af[mt] = *reinterpret_cast<const short8*>(&Alds[row * AST + lg * 8]);
    }
    #pragma unroll
    for (int nt = 0; nt < 3; ++nt) {
      const int row = wc * 48 + nt * 16 + l15;
      bf[nt] = *reinterpret_cast<const short8*>(&Blds[row * BST + lg * 8]);
    }
    #pragma unroll
    for (int mt = 0; mt < 4; ++mt)
      #pragma unroll
      for (int nt = 0; nt < 3; ++nt)
        acc[mt][nt] = __builtin_amdgcn_mfma_f32_16x16x32_bf16(
            af[mt], bf[nt], acc[mt][nt], 0, 0, 0);
    __syncthreads();
  }

  // ---- BatchNorm stats: mean/var over batch per (c, col) ----
  // C/D layout: col = lane&15, row_in_tile = lg*4 + reg   (m89-verified)
  #pragma unroll
  for (int nt = 0; nt < 3; ++nt) {
    float s = 0.f, q = 0.f;
    #pragma unroll
    for (int mt = 0; mt < 4; ++mt)
      #pragma unroll
      for (int r = 0; r < 4; ++r) {
        const float v = acc[mt][nt][r];
        s += v; q += v * v;
      }
    s += __shfl_xor(s, 16); q += __shfl_xor(q, 16);
    s += __shfl_xor(s, 32); q += __shfl_xor(q, 32);
    if (lg == 0) {
      const int col = wc * 48 + nt * 16 + l15;
      psum[wr][col] = s;
      psq [wr][col] = q;
    }
  }
  __syncthreads();

  if (tid < FHID) {
    const float s  = psum[0][tid] + psum[1][tid] + psum[2][tid] + psum[3][tid];
    const float q  = psq [0][tid] + psq [1][tid] + psq [2][tid] + psq [3][tid];
    const float mean = s * (1.f / 256.f);
    const float var  = q * (1.f / 256.f) - mean * mean;   // biased
    const float rstd = rsqrtf(var + EPS);
    const float sc   = rstd * gamma[(size_t)c * FHID + tid];
    scaleS[tid] = sc;
    shiftS[tid] = beta[(size_t)c * FHID + tid] - mean * sc;
    w2S[tid]    = W2[(size_t)c * FHID + tid];
  }
  __syncthreads();

  // ---- normalize + ReLU + dot(W2) epilogue ----
  #pragma unroll
  for (int mt = 0; mt < 4; ++mt) {
    #pragma unroll
    for (int r = 0; r < 4; ++r) {
      float p = 0.f;
      #pragma unroll
      for (int nt = 0; nt < 3; ++nt) {
        const int col = wc * 48 + nt * 16 + l15;
        float v = acc[mt][nt][r] * scaleS[col] + shiftS[col];
        v = fmaxf(v, 0.f);
        p += v * w2S[col];
      }
      p += __shfl_xor(p, 1);
      p += __shfl_xor(p, 2);
      p += __shfl_xor(p, 4);
      p += __shfl_xor(p, 8);
      if (l15 == 0) {
        const int row = wr * 64 + mt * 16 + lg * 4 + r;
        rowp[wc][row] = p;
      }
    }
  }
  __syncthreads();

  if (tid < B_DIM) {
    const float o = rowp[0][tid] + rowp[1][tid] + rowp[2][tid] + rowp[3][tid] + b2[c];
    out[(size_t)tid * C_DIM + c] = o;
  }
}

extern "C" void kernel_launch(void* const* d_in, const int* in_sizes, int n_in,
                              void* d_out, int out_size, void* d_ws, size_t ws_size,
                              hipStream_t stream) {
  const float* x     = (const float*)d_in[0];
  const float* W1    = (const float*)d_in[1];
  const float* gamma = (const float*)d_in[2];
  const float* beta  = (const float*)d_in[3];
  const float* W2    = (const float*)d_in[4];
  const float* b2    = (const float*)d_in[5];
  float* out = (float*)d_out;
  mlp_fused_kernel<<<C_DIM, 1024, 0, stream>>>(x, W1, gamma, beta, W2, b2, out);
}